// Round 3
// baseline (344.740 us; speedup 1.0000x reference)
//
#include <hip/hip_runtime.h>
#include <hip/hip_cooperative_groups.h>
#include <math.h>

namespace cg = cooperative_groups;

constexpr int B = 4;
constexpr int N = 8192;
constexpr int KNN = 8;
constexpr int NCELL = 4096;              // 16^3 Morton cells
constexpr int GSIZE = 16;                // points per group
constexpr int NGRP = N / GSIZE;          // 512 groups per cloud-batch
constexpr int NSUP = 64;                 // supers of 8 groups (128 pts)
constexpr int NCB = 2 * B;               // cloud-batches (0-3 pred, 4-7 tgt)

// Insert tv into sorted ascending d[0..7]. Exact: d'[0]=min(d0,tv),
// d'[i]=med3(d[i-1],d[i],tv). 8 independent ops.
__device__ __forceinline__ void insert8(float (&d)[KNN], float tv) {
  float n0 = fminf(d[0], tv);
  float n1 = __builtin_amdgcn_fmed3f(d[0], d[1], tv);
  float n2 = __builtin_amdgcn_fmed3f(d[1], d[2], tv);
  float n3 = __builtin_amdgcn_fmed3f(d[2], d[3], tv);
  float n4 = __builtin_amdgcn_fmed3f(d[3], d[4], tv);
  float n5 = __builtin_amdgcn_fmed3f(d[4], d[5], tv);
  float n6 = __builtin_amdgcn_fmed3f(d[5], d[6], tv);
  float n7 = __builtin_amdgcn_fmed3f(d[6], d[7], tv);
  d[0] = n0; d[1] = n1; d[2] = n2; d[3] = n3;
  d[4] = n4; d[5] = n5; d[6] = n6; d[7] = n7;
}

__device__ __forceinline__ int morton3(int x, int y, int z) {
  int m = 0;
#pragma unroll
  for (int b = 0; b < 4; ++b)
    m |= (((x >> b) & 1) << (3 * b + 2)) | (((y >> b) & 1) << (3 * b + 1)) |
         (((z >> b) & 1) << (3 * b + 0));
  return m;
}

// One cooperative kernel replaces the 5-kernel prep pipeline:
// Z zero-hist -> H histogram -> S scan (starts+cursor) -> X scatter -> B boxes.
// 64 blocks x 1024 threads; thread gid owns point gid and keeps it in regs
// across phases (no cellid spill array).
__global__ __launch_bounds__(1024) void prep_kernel(
    const float* __restrict__ src, const float* __restrict__ tgt,
    const float* __restrict__ flow, float4* __restrict__ pred_s,
    float4* __restrict__ tgt_s, int* __restrict__ hist,
    int* __restrict__ cursor, int* __restrict__ starts,
    float4* __restrict__ gbox, float4* __restrict__ sbox,
    float* __restrict__ out) {
  cg::grid_group grid = cg::this_grid();
  __shared__ int wsum[16];
  int tid = threadIdx.x, bid = blockIdx.x;
  int gid = bid * 1024 + tid;                 // 0..65535

  if (gid == 0) out[0] = 0.0f;
  if (gid < NCB * NCELL) hist[gid] = 0;       // Phase Z

  int cb = gid >> 13, idx = gid & (N - 1);
  int cloud = cb >> 2, batch = cb & 3;
  const float* __restrict__ bp = (cloud == 0 ? src : tgt) + batch * N * 3;
  float x = bp[3 * idx + 0], y = bp[3 * idx + 1], z = bp[3 * idx + 2];
  if (cloud == 0) {
    const float* __restrict__ bf = flow + batch * N * 3;
    x += bf[3 * idx + 0]; y += bf[3 * idx + 1]; z += bf[3 * idx + 2];
  }
  int cx = (int)fminf(fmaxf((x + 4.0f) * 2.0f, 0.0f), 15.0f);
  int cy = (int)fminf(fmaxf((y + 4.0f) * 2.0f, 0.0f), 15.0f);
  int cz = (int)fminf(fmaxf((z + 4.0f) * 2.0f, 0.0f), 15.0f);
  int cell = morton3(cx, cy, cz);

  grid.sync();
  atomicAdd(&hist[cb * NCELL + cell], 1);     // Phase H
  grid.sync();

  if (bid < NCB) {                            // Phase S: scan 4096 bins of cb=bid
    int base = bid * NCELL + tid * 4;
    int v0 = hist[base + 0], v1 = hist[base + 1];
    int v2 = hist[base + 2], v3 = hist[base + 3];
    int s = v0 + v1 + v2 + v3;
    int lane = tid & 63, w = tid >> 6;
    int incl = s;
    for (int off = 1; off < 64; off <<= 1) {
      int u = __shfl_up(incl, off, 64);
      if (lane >= off) incl += u;
    }
    if (lane == 63) wsum[w] = incl;
    __syncthreads();
    if (tid < 16) {
      int xv = wsum[tid], inc = xv;
      for (int off = 1; off < 16; off <<= 1) {
        int u = __shfl_up(inc, off, 64);
        if (tid >= off) inc += u;
      }
      wsum[tid] = inc - xv;                   // exclusive wave offset
    }
    __syncthreads();
    int run = incl - s + wsum[w];
    int sb_ = bid * (NCELL + 1) + tid * 4;
    starts[sb_ + 0] = run; cursor[base + 0] = run; run += v0;
    starts[sb_ + 1] = run; cursor[base + 1] = run; run += v1;
    starts[sb_ + 2] = run; cursor[base + 2] = run; run += v2;
    starts[sb_ + 3] = run; cursor[base + 3] = run; run += v3;
    if (tid == 1023) starts[bid * (NCELL + 1) + NCELL] = N;
  }
  grid.sync();

  int pos = atomicAdd(&cursor[cb * NCELL + cell], 1);   // Phase X
  float4* __restrict__ dst = (cloud == 0 ? pred_s : tgt_s) + batch * N;
  dst[pos] = make_float4(x, y, z, 0.5f * (x * x + y * y + z * z));
  grid.sync();

  if (gid < NCB * NGRP) {                     // Phase B: 4096 group AABBs
    int bcb = gid >> 9, g = gid & (NGRP - 1);
    const float4* __restrict__ sp =
        (bcb < 4 ? pred_s : tgt_s) + (bcb & 3) * N + g * GSIZE;
    float lx = INFINITY, ly = INFINITY, lz = INFINITY;
    float hx = -INFINITY, hy = -INFINITY, hz = -INFINITY;
#pragma unroll
    for (int j = 0; j < GSIZE; ++j) {
      float4 p = sp[j];
      lx = fminf(lx, p.x); ly = fminf(ly, p.y); lz = fminf(lz, p.z);
      hx = fmaxf(hx, p.x); hy = fmaxf(hy, p.y); hz = fmaxf(hz, p.z);
    }
    gbox[2 * gid + 0] = make_float4(lx, ly, lz, 0.0f);
    gbox[2 * gid + 1] = make_float4(hx, hy, hz, 0.0f);
  } else if (gid < NCB * NGRP + NCB * NSUP) { // 512 super AABBs (128 pts each)
    int k = gid - NCB * NGRP;
    int bcb = k >> 6, sg = k & (NSUP - 1);
    const float4* __restrict__ sp =
        (bcb < 4 ? pred_s : tgt_s) + (bcb & 3) * N + sg * 128;
    float lx = INFINITY, ly = INFINITY, lz = INFINITY;
    float hx = -INFINITY, hy = -INFINITY, hz = -INFINITY;
    for (int j = 0; j < 128; ++j) {
      float4 p = sp[j];
      lx = fminf(lx, p.x); ly = fminf(ly, p.y); lz = fminf(lz, p.z);
      hx = fmaxf(hx, p.x); hy = fmaxf(hy, p.y); hz = fmaxf(hz, p.z);
    }
    sbox[2 * k + 0] = make_float4(lx, ly, lz, 0.0f);
    sbox[2 * k + 1] = make_float4(hx, hy, hz, 0.0f);
  }
}

// Per-LANE best-first KNN over rank groups. lane l and l+32 share query
// gq = wg*32 + (lane&31), partitioning candidate groups by parity (disjoint ->
// no duplicate insertion; each half's box-skips justified by its own thr >=
// merged d8 -> exact). Per-lane worklist in LDS: drain cost = wave-MAX of
// per-lane counts, not the 64-query union.
__global__ __launch_bounds__(256) void chamfer_kernel(
    const float4* __restrict__ pred_s, const float4* __restrict__ tgt_s,
    const int* __restrict__ starts, const float4* __restrict__ gbox,
    const float4* __restrict__ sbox, float* __restrict__ out) {
  constexpr int CAP = 16;
  __shared__ int wl[256][CAP + 1];            // +1 pad: avoid 2-bank aliasing
  int tid = threadIdx.x;
  int lane = tid & 63;
  int wv = tid >> 6;
  int par = lane >> 5;
  int wg = blockIdx.x * 4 + wv;               // 0..2047
  int gq = wg * 32 + (lane & 31);             // 0..65535
  int qcb = gq >> 13;
  int idx = gq & (N - 1);
  int ccb = qcb ^ 4;                          // opposite cloud, same batch
  const float4* __restrict__ qarr = (qcb < 4 ? pred_s : tgt_s) + (qcb & 3) * N;
  const float4* __restrict__ parr = (ccb < 4 ? pred_s : tgt_s) + (ccb & 3) * N;
  const int* __restrict__ st = starts + ccb * (NCELL + 1);
  const float4* __restrict__ gb = gbox + ccb * (2 * NGRP);
  const float4* __restrict__ sb = sbox + ccb * (2 * NSUP);

  float4 q = qarr[idx];
  float nqx = -q.x, nqy = -q.y, nqz = -q.z, twoqw = 2.0f * q.w;

  float d[KNN];
#pragma unroll
  for (int i = 0; i < KNN; ++i) d[i] = INFINITY;

  auto process = [&](int g) {
    const float4* __restrict__ gp = parr + g * GSIZE;
#pragma unroll
    for (int j = 0; j < GSIZE; ++j) {
      float4 p = gp[j];
      float tv = __builtin_fmaf(nqx, p.x, __builtin_fmaf(nqy, p.y,
                 __builtin_fmaf(nqz, p.z, p.w)));
      insert8(d, tv);
    }
  };
  auto boxmd = [&](const float4* __restrict__ bx) {
    float4 lo = bx[0], hi = bx[1];
    float ax = fmaxf(fmaxf(lo.x - q.x, q.x - hi.x), 0.0f);
    float ay = fmaxf(fmaxf(lo.y - q.y, q.y - hi.y), 0.0f);
    float az = fmaxf(fmaxf(lo.z - q.z, q.z - hi.z), 0.0f);
    return __builtin_fmaf(ax, ax, __builtin_fmaf(ay, ay, az * az));
  };

  // Seed: candidate groups at q's Morton cell (density-adaptive rank match).
  int qcx = (int)fminf(fmaxf((q.x + 4.0f) * 2.0f, 0.0f), 15.0f);
  int qcy = (int)fminf(fmaxf((q.y + 4.0f) * 2.0f, 0.0f), 15.0f);
  int qcz = (int)fminf(fmaxf((q.z + 4.0f) * 2.0f, 0.0f), 15.0f);
  int ge = st[morton3(qcx, qcy, qcz)] >> 4;
  ge = min(max(ge & ~1, 0), NGRP - 4);
  int s0 = ge + par, s1 = ge + 2 + par;       // this half's 2 seed groups
  process(s0);
  process(s1);
  float thr = __builtin_fmaf(2.0f, d[KNN - 1], twoqw) * 1.00001f + 1e-5f;

  // Sweep all 64 supers vs own thr; descend to own-parity groups; worklist.
  int cnt = 0;
  for (int s = 0; s < NSUP; ++s) {
    float mds = boxmd(sb + 2 * s);
    if (mds < thr) {
#pragma unroll
      for (int j = 0; j < 4; ++j) {
        int g = s * 8 + j * 2 + par;
        if (g == s0 || g == s1) continue;
        float md = boxmd(gb + 2 * g);
        if (md < thr) {
          if (cnt < CAP) {
            wl[tid][cnt] = g; ++cnt;
          } else {                             // rare overflow: process now
            process(g);
            thr = __builtin_fmaf(2.0f, d[KNN - 1], twoqw) * 1.00001f + 1e-5f;
          }
        }
      }
    }
  }

  // Drain worklists: wave-max iterations, re-check boxes vs tightened thr.
  for (int k = 0;; ++k) {
    if (__ballot(k < cnt) == 0ull) break;
    if (k < cnt) {
      int g = wl[tid][k];
      if (boxmd(gb + 2 * g) < thr) {
        process(g);
        thr = __builtin_fmaf(2.0f, d[KNN - 1], twoqw) * 1.00001f + 1e-5f;
      }
    }
  }

  // Merge the two halves' disjoint top-8 lists (exchange originals first!).
  float od[KNN];
#pragma unroll
  for (int i = 0; i < KNN; ++i) od[i] = __shfl_xor(d[i], 32, 64);
#pragma unroll
  for (int i = 0; i < KNN; ++i) insert8(d, od[i]);

  float s_ = 0.0f;
#pragma unroll
  for (int i = 0; i < KNN; ++i) {
    float d2 = fmaxf(__builtin_fmaf(2.0f, d[i], twoqw), 0.0f);
    s_ += sqrtf(d2);
  }
  float val = (par == 0) ? s_ * (1.0f / KNN) : 0.0f;
  for (int off = 32; off; off >>= 1) val += __shfl_down(val, off, 64);
  if (lane == 0) atomicAdd(out, val * (1.0f / (B * N)));
}

extern "C" void kernel_launch(void* const* d_in, const int* in_sizes, int n_in,
                              void* d_out, int out_size, void* d_ws, size_t ws_size,
                              hipStream_t stream) {
  const float* src = (const float*)d_in[0];
  const float* tgt = (const float*)d_in[1];
  const float* flow = (const float*)d_in[2];
  float* out = (float*)d_out;

  float4* pred_s = (float4*)d_ws;                        // 512 KB
  float4* tgt_s = pred_s + B * N;                        // 512 KB
  float4* gbox = tgt_s + B * N;                          // 8*512*2*16B = 128 KB
  float4* sbox = gbox + NCB * 2 * NGRP;                  // 8*64*2*16B = 16 KB
  int* starts = (int*)(sbox + NCB * 2 * NSUP);           // 8*4097*4 = 131 KB
  int* hist = starts + NCB * (NCELL + 1);                // 128 KB
  int* cursor = hist + NCB * NCELL;                      // 128 KB

  void* args[] = {(void*)&src,    (void*)&tgt,   (void*)&flow,
                  (void*)&pred_s, (void*)&tgt_s, (void*)&hist,
                  (void*)&cursor, (void*)&starts, (void*)&gbox,
                  (void*)&sbox,   (void*)&out};
  hipLaunchCooperativeKernel((void*)prep_kernel, dim3(64), dim3(1024), args, 0,
                             stream);
  chamfer_kernel<<<512, 256, 0, stream>>>(pred_s, tgt_s, starts, gbox, sbox, out);
}

// Round 4
// 206.429 us; speedup vs baseline: 1.6700x; 1.6700x over previous
//
#include <hip/hip_runtime.h>
#include <math.h>

constexpr int B = 4;
constexpr int N = 8192;
constexpr int KNN = 8;
constexpr int NCELL = 4096;              // 16^3 Morton cells
constexpr int GSIZE = 16;                // points per group
constexpr int NGRP = N / GSIZE;          // 512 groups per cloud-batch
constexpr int NSUP = 64;                 // supers: 8 groups (128 pts)
constexpr int NHYP = 8;                  // hypers: 8 supers (1024 pts)
constexpr int NCB = 2 * B;               // cloud-batches (0-3 pred, 4-7 tgt)

// Insert tv into sorted ascending d[0..7]. Exact: d'[0]=min(d0,tv),
// d'[i]=med3(d[i-1],d[i],tv). 8 independent ops.
__device__ __forceinline__ void insert8(float (&d)[KNN], float tv) {
  float n0 = fminf(d[0], tv);
  float n1 = __builtin_amdgcn_fmed3f(d[0], d[1], tv);
  float n2 = __builtin_amdgcn_fmed3f(d[1], d[2], tv);
  float n3 = __builtin_amdgcn_fmed3f(d[2], d[3], tv);
  float n4 = __builtin_amdgcn_fmed3f(d[3], d[4], tv);
  float n5 = __builtin_amdgcn_fmed3f(d[4], d[5], tv);
  float n6 = __builtin_amdgcn_fmed3f(d[5], d[6], tv);
  float n7 = __builtin_amdgcn_fmed3f(d[6], d[7], tv);
  d[0] = n0; d[1] = n1; d[2] = n2; d[3] = n3;
  d[4] = n4; d[5] = n5; d[6] = n6; d[7] = n7;
}

__device__ __forceinline__ int morton3(int x, int y, int z) {
  int m = 0;
#pragma unroll
  for (int b = 0; b < 4; ++b)
    m |= (((x >> b) & 1) << (3 * b + 2)) | (((y >> b) & 1) << (3 * b + 1)) |
         (((z >> b) & 1) << (3 * b + 0));
  return m;
}

__device__ __forceinline__ int point_cell(float x, float y, float z) {
  int cx = (int)fminf(fmaxf((x + 4.0f) * 2.0f, 0.0f), 15.0f);
  int cy = (int)fminf(fmaxf((y + 4.0f) * 2.0f, 0.0f), 15.0f);
  int cz = (int)fminf(fmaxf((z + 4.0f) * 2.0f, 0.0f), 15.0f);
  return morton3(cx, cy, cz);
}

// One block per cloud-batch (8 blocks x 1024 threads). Each cb is fully
// independent: LDS histogram -> in-block scan (cursor + global starts) ->
// scatter (points kept in registers) -> group/super/hyper AABBs.
// No grid.sync, no extra launches.
__global__ __launch_bounds__(1024) void prep_kernel(
    const float* __restrict__ src, const float* __restrict__ tgt,
    const float* __restrict__ flow, float4* __restrict__ pred_s,
    float4* __restrict__ tgt_s, int* __restrict__ starts,
    float4* __restrict__ gbox, float4* __restrict__ sbox,
    float4* __restrict__ hbox, float* __restrict__ out) {
  __shared__ int hist[NCELL];              // 16 KB: counts -> cursor
  __shared__ int wsum[16];
  __shared__ float4 gcache[2 * NGRP];      // 16 KB
  __shared__ float4 scache[2 * NSUP];      // 2 KB
  int tid = threadIdx.x, cb = blockIdx.x;
  int cloud = cb >> 2, batch = cb & 3;
  if (cb == 0 && tid == 0) out[0] = 0.0f;

  for (int i = tid; i < NCELL; i += 1024) hist[i] = 0;
  __syncthreads();

  const float* __restrict__ bp = (cloud == 0 ? src : tgt) + batch * N * 3;
  const float* __restrict__ bf = flow + batch * N * 3;
  float4 pt[8];
  int cell[8];
#pragma unroll
  for (int k = 0; k < 8; ++k) {
    int i = k * 1024 + tid;
    float x = bp[3 * i + 0], y = bp[3 * i + 1], z = bp[3 * i + 2];
    if (cloud == 0) { x += bf[3 * i + 0]; y += bf[3 * i + 1]; z += bf[3 * i + 2]; }
    pt[k] = make_float4(x, y, z, 0.5f * (x * x + y * y + z * z));
    cell[k] = point_cell(x, y, z);
    atomicAdd(&hist[cell[k]], 1);
  }
  __syncthreads();

  // In-block exclusive scan of 4096 bins (4 per thread).
  int b4 = tid * 4;
  int h0v = hist[b4 + 0], h1v = hist[b4 + 1];
  int h2v = hist[b4 + 2], h3v = hist[b4 + 3];
  int s = h0v + h1v + h2v + h3v;
  int lane = tid & 63, w = tid >> 6;
  int incl = s;
#pragma unroll
  for (int off = 1; off < 64; off <<= 1) {
    int u = __shfl_up(incl, off, 64);
    if (lane >= off) incl += u;
  }
  if (lane == 63) wsum[w] = incl;
  __syncthreads();
  if (tid < 16) {
    int v = wsum[tid], inc = v;
#pragma unroll
    for (int off = 1; off < 16; off <<= 1) {
      int u = __shfl_up(inc, off, 64);
      if (tid >= off) inc += u;
    }
    wsum[tid] = inc - v;                   // exclusive wave offset
  }
  __syncthreads();
  int run = incl - s + wsum[w];
  int* __restrict__ stg = starts + cb * (NCELL + 1);
  stg[b4 + 0] = run; hist[b4 + 0] = run; run += h0v;
  stg[b4 + 1] = run; hist[b4 + 1] = run; run += h1v;
  stg[b4 + 2] = run; hist[b4 + 2] = run; run += h2v;
  stg[b4 + 3] = run; hist[b4 + 3] = run; run += h3v;
  if (tid == 0) stg[NCELL] = N;
  __syncthreads();

  // Scatter (cb-private output range).
  float4* __restrict__ dst = (cloud == 0 ? pred_s : tgt_s) + batch * N;
#pragma unroll
  for (int k = 0; k < 8; ++k) {
    int pos = atomicAdd(&hist[cell[k]], 1);
    dst[pos] = pt[k];
  }
  __threadfence_block();
  __syncthreads();

  // Group AABBs (512), then supers (64), then hypers (8).
  if (tid < NGRP) {
    const float4* __restrict__ sp = dst + tid * GSIZE;
    float lx = INFINITY, ly = INFINITY, lz = INFINITY;
    float hx = -INFINITY, hy = -INFINITY, hz = -INFINITY;
#pragma unroll
    for (int t = 0; t < GSIZE; ++t) {
      float4 p = sp[t];
      lx = fminf(lx, p.x); ly = fminf(ly, p.y); lz = fminf(lz, p.z);
      hx = fmaxf(hx, p.x); hy = fmaxf(hy, p.y); hz = fmaxf(hz, p.z);
    }
    float4 lo = make_float4(lx, ly, lz, 0.0f);
    float4 hi = make_float4(hx, hy, hz, 0.0f);
    gcache[2 * tid] = lo; gcache[2 * tid + 1] = hi;
    gbox[cb * 2 * NGRP + 2 * tid + 0] = lo;
    gbox[cb * 2 * NGRP + 2 * tid + 1] = hi;
  }
  __syncthreads();
  if (tid < NSUP) {
    float lx = INFINITY, ly = INFINITY, lz = INFINITY;
    float hx = -INFINITY, hy = -INFINITY, hz = -INFINITY;
#pragma unroll
    for (int t = 0; t < 8; ++t) {
      float4 lo = gcache[2 * (tid * 8 + t)], hi = gcache[2 * (tid * 8 + t) + 1];
      lx = fminf(lx, lo.x); ly = fminf(ly, lo.y); lz = fminf(lz, lo.z);
      hx = fmaxf(hx, hi.x); hy = fmaxf(hy, hi.y); hz = fmaxf(hz, hi.z);
    }
    float4 lo = make_float4(lx, ly, lz, 0.0f);
    float4 hi = make_float4(hx, hy, hz, 0.0f);
    scache[2 * tid] = lo; scache[2 * tid + 1] = hi;
    sbox[cb * 2 * NSUP + 2 * tid + 0] = lo;
    sbox[cb * 2 * NSUP + 2 * tid + 1] = hi;
  }
  __syncthreads();
  if (tid < NHYP) {
    float lx = INFINITY, ly = INFINITY, lz = INFINITY;
    float hx = -INFINITY, hy = -INFINITY, hz = -INFINITY;
#pragma unroll
    for (int t = 0; t < 8; ++t) {
      float4 lo = scache[2 * (tid * 8 + t)], hi = scache[2 * (tid * 8 + t) + 1];
      lx = fminf(lx, lo.x); ly = fminf(ly, lo.y); lz = fminf(lz, lo.z);
      hx = fmaxf(hx, hi.x); hy = fmaxf(hy, hi.y); hz = fmaxf(hz, hi.z);
    }
    hbox[cb * 2 * NHYP + 2 * tid + 0] = make_float4(lx, ly, lz, 0.0f);
    hbox[cb * 2 * NHYP + 2 * tid + 1] = make_float4(hx, hy, hz, 0.0f);
  }
}

// 8 lanes per query (lane j owns groups g === j mod 8; one group per super).
// Seed = the rank-matched super's 8 groups (one per lane) -> shared thr after
// min-reduce is the true d8 of the 128 nearest-rank points. Hierarchy
// hyper(1024) -> super(128) -> group(16) prunes with hyper-min <= super-min <=
// group-min <= true dist^2, vs a monotone non-increasing shared thr >= final
// merged d8 (merged 8th <= every subset 8th) => every skip is exact
// (1e-5 margins cover fp rounding).
__global__ __launch_bounds__(256, 6) void chamfer_kernel(
    const float4* __restrict__ pred_s, const float4* __restrict__ tgt_s,
    const int* __restrict__ starts, const float4* __restrict__ gbox,
    const float4* __restrict__ sbox, const float4* __restrict__ hbox,
    float* __restrict__ out) {
  __shared__ float bsum[4];
  int tid = threadIdx.x;
  int lane = tid & 63;
  int j = lane & 7;                          // sub-lane within the query octet
  int wgid = blockIdx.x * 4 + (tid >> 6);    // 0..8191
  int gq = wgid * 8 + (lane >> 3);           // 0..65535 (8 queries per wave)
  int qcb = gq >> 13, idx = gq & (N - 1);
  int ccb = qcb ^ 4;                         // opposite cloud, same batch
  const float4* __restrict__ qarr = (qcb < 4 ? pred_s : tgt_s) + (qcb & 3) * N;
  const float4* __restrict__ parr = (ccb < 4 ? pred_s : tgt_s) + (ccb & 3) * N;
  const int* __restrict__ st = starts + ccb * (NCELL + 1);
  const float4* __restrict__ gb = gbox + ccb * (2 * NGRP);
  const float4* __restrict__ sb = sbox + ccb * (2 * NSUP);
  const float4* __restrict__ hb = hbox + ccb * (2 * NHYP);

  float4 q = qarr[idx];
  float nqx = -q.x, nqy = -q.y, nqz = -q.z, twoqw = 2.0f * q.w;
  float d[KNN];
#pragma unroll
  for (int i = 0; i < KNN; ++i) d[i] = INFINITY;

  auto process = [&](int g) {                // 16 pts, 2 batches of 8 in flight
    const float4* __restrict__ gp = parr + (g << 4);
    float4 P[8];
#pragma unroll
    for (int t = 0; t < 8; ++t) P[t] = gp[t];
#pragma unroll
    for (int t = 0; t < 8; ++t) {
      float tv = __builtin_fmaf(nqx, P[t].x, __builtin_fmaf(nqy, P[t].y,
                 __builtin_fmaf(nqz, P[t].z, P[t].w)));
      insert8(d, tv);
    }
#pragma unroll
    for (int t = 0; t < 8; ++t) P[t] = gp[8 + t];
#pragma unroll
    for (int t = 0; t < 8; ++t) {
      float tv = __builtin_fmaf(nqx, P[t].x, __builtin_fmaf(nqy, P[t].y,
                 __builtin_fmaf(nqz, P[t].z, P[t].w)));
      insert8(d, tv);
    }
  };
  auto boxmd = [&](const float4* __restrict__ bx) {
    float4 lo = bx[0], hi = bx[1];
    float ax = fmaxf(fmaxf(lo.x - q.x, q.x - hi.x), 0.0f);
    float ay = fmaxf(fmaxf(lo.y - q.y, q.y - hi.y), 0.0f);
    float az = fmaxf(fmaxf(lo.z - q.z, q.z - hi.z), 0.0f);
    return __builtin_fmaf(ax, ax, __builtin_fmaf(ay, ay, az * az));
  };

  // Seed: the rank-matched super, one group per sub-lane.
  int ge = st[point_cell(q.x, q.y, q.z)];
  int s0 = min(ge >> 7, NSUP - 1);
  int gseed = s0 * 8 + j;
  process(gseed);
  float myt = __builtin_fmaf(2.0f, d[KNN - 1], twoqw) * 1.00001f + 1e-5f;
  float thr = myt;
#pragma unroll
  for (int m = 1; m < 8; m <<= 1) thr = fminf(thr, __shfl_xor(thr, m, 64));

  int h0 = s0 >> 3;
  for (int k = 0; k < NHYP; ++k) {
    int h = (h0 + k) & (NHYP - 1);           // rank-matched hyper first
    float mdh = boxmd(hb + 2 * h);
    if (__ballot(mdh < thr) == 0ull) continue;
    for (int s8 = 0; s8 < 8; ++s8) {
      int sg = h * 8 + s8;
      float mds = boxmd(sb + 2 * sg);
      if (__ballot(mds < thr) == 0ull) continue;
      int g = sg * 8 + j;
      float mdg = boxmd(gb + 2 * g);
      bool go = (mdg < thr) && (g != gseed);
      if (__ballot(go) != 0ull) {
        if (go) {
          process(g);
          myt = __builtin_fmaf(2.0f, d[KNN - 1], twoqw) * 1.00001f + 1e-5f;
        }
        float t2 = myt;
#pragma unroll
        for (int m = 1; m < 8; m <<= 1) t2 = fminf(t2, __shfl_xor(t2, m, 64));
        thr = t2;
      }
    }
  }

  // Tree-merge the 8 disjoint subset top-8s within the octet.
#pragma unroll
  for (int m = 1; m < 8; m <<= 1) {
    float od[KNN];
#pragma unroll
    for (int i = 0; i < KNN; ++i) od[i] = __shfl_xor(d[i], m, 64);
#pragma unroll
    for (int i = 0; i < KNN; ++i) insert8(d, od[i]);
  }

  float val = 0.0f;
  if (j == 0) {
    float s_ = 0.0f;
#pragma unroll
    for (int i = 0; i < KNN; ++i) {
      float d2 = fmaxf(__builtin_fmaf(2.0f, d[i], twoqw), 0.0f);
      s_ += sqrtf(d2);
    }
    val = s_ * (1.0f / KNN);
  }
  for (int off = 32; off; off >>= 1) val += __shfl_down(val, off, 64);
  if (lane == 0) bsum[tid >> 6] = val;
  __syncthreads();
  if (tid == 0)
    atomicAdd(out, (bsum[0] + bsum[1] + bsum[2] + bsum[3]) * (1.0f / (B * N)));
}

extern "C" void kernel_launch(void* const* d_in, const int* in_sizes, int n_in,
                              void* d_out, int out_size, void* d_ws, size_t ws_size,
                              hipStream_t stream) {
  const float* src = (const float*)d_in[0];
  const float* tgt = (const float*)d_in[1];
  const float* flow = (const float*)d_in[2];
  float* out = (float*)d_out;

  float4* pred_s = (float4*)d_ws;                        // 512 KB
  float4* tgt_s = pred_s + B * N;                        // 512 KB
  float4* gbox = tgt_s + B * N;                          // 128 KB
  float4* sbox = gbox + NCB * 2 * NGRP;                  // 16 KB
  float4* hbox = sbox + NCB * 2 * NSUP;                  // 2 KB
  int* starts = (int*)(hbox + NCB * 2 * NHYP);           // 131 KB

  prep_kernel<<<NCB, 1024, 0, stream>>>(src, tgt, flow, pred_s, tgt_s, starts,
                                        gbox, sbox, hbox, out);
  chamfer_kernel<<<2048, 256, 0, stream>>>(pred_s, tgt_s, starts, gbox, sbox,
                                           hbox, out);
}